// Round 1
// baseline (326.176 us; speedup 1.0000x reference)
//
#include <hip/hip_runtime.h>

#define FH 200
#define FW 200
#define FC 256
#define NBIN 49      // 7*7 output bins
#define NSAMP 196    // NBIN * 4 subsamples

// ---------------------------------------------------------------------------
// Per-sample geometry: weights (pre-multiplied by valid-mask and 0.25 mean
// factor) and the 4 bilinear-corner pixel offsets. Matches the JAX reference
// exactly (aligned/continuous coords, clamp-at-edge, valid in [-1, H]).
// ---------------------------------------------------------------------------
__device__ __forceinline__ void compute_sample(const float* __restrict__ roi,
                                               int s, bool nhwc,
                                               float4* wout, int4* oout)
{
    int   b  = (int)roi[0];
    float cw = roi[1] * 0.25f - 0.5f;
    float ch = roi[2] * 0.25f - 0.5f;
    float rw = fmaxf(roi[3] * 0.25f, 1.0f);
    float rh = fmaxf(roi[4] * 0.25f, 1.0f);
    float th = roi[5] * 0.017453292519943295f;   // pi/180
    float ct = cosf(th);
    float st = sinf(th);
    float bin_h = rh / 7.0f;
    float bin_w = rw / 7.0f;

    int bin = s >> 2;
    int sub = s & 3;
    int iy  = sub >> 1;
    int ix  = sub & 1;
    int ph  = bin / 7;
    int pw  = bin - ph * 7;

    float fy = 0.25f + 0.5f * (float)iy;  // frac = {0.25, 0.75}
    float fx = 0.25f + 0.5f * (float)ix;
    float yy = -rh * 0.5f + ((float)ph + fy) * bin_h;
    float xx = -rw * 0.5f + ((float)pw + fx) * bin_w;
    float y  = yy * ct - xx * st + ch;
    float x  = yy * st + xx * ct + cw;

    bool valid = (y >= -1.0f) && (y <= (float)FH) && (x >= -1.0f) && (x <= (float)FW);
    y = fmaxf(y, 0.0f);
    x = fmaxf(x, 0.0f);
    int y0 = (int)floorf(y);
    int x0 = (int)floorf(x);
    bool cy = (y0 >= FH - 1);
    bool cx = (x0 >= FW - 1);
    int ylo = cy ? (FH - 1) : y0;
    int yhi = cy ? (FH - 1) : (y0 + 1);
    int xlo = cx ? (FW - 1) : x0;
    int xhi = cx ? (FW - 1) : (x0 + 1);
    float ly = cy ? 0.0f : (y - (float)y0);
    float lx = cx ? 0.0f : (x - (float)x0);
    float hy = 1.0f - ly;
    float hx = 1.0f - lx;
    float m  = valid ? 0.25f : 0.0f;   // fold valid-mask + mean(4 samples)

    *wout = make_float4(hy * hx * m, hy * lx * m, ly * hx * m, ly * lx * m);

    int bb = b * (FC * FH * FW);
    int p0 = ylo * FW + xlo;
    int p1 = ylo * FW + xhi;
    int p2 = yhi * FW + xlo;
    int p3 = yhi * FW + xhi;
    if (nhwc)
        *oout = make_int4(bb + p0 * FC, bb + p1 * FC, bb + p2 * FC, bb + p3 * FC);
    else
        *oout = make_int4(bb + p0, bb + p1, bb + p2, bb + p3);
}

__device__ __forceinline__ float fixnum(float v)
{
    // nan_to_num(nan/±inf -> 1e-8)
    return (v == v && v <= 3.402823466e38f && v >= -3.402823466e38f) ? v : 1e-8f;
}

// ---------------------------------------------------------------------------
// NCHW [N,C,H,W] -> NHWC [N,H*W,C] transpose, 32x32 LDS tiles.
// grid (HW/32, C/32, N), block (32, 8).
// ---------------------------------------------------------------------------
__global__ __launch_bounds__(256)
void transpose_kernel(const float* __restrict__ in, float* __restrict__ out)
{
    __shared__ float tile[32][33];
    int b  = blockIdx.z;
    int p0 = blockIdx.x * 32;   // pixel index (y*W + x)
    int c0 = blockIdx.y * 32;   // channel index
    int tx = threadIdx.x;       // 0..31
    int ty = threadIdx.y;       // 0..7

    const float* inb  = in  + (size_t)b * FC * (FH * FW);
    float*       outb = out + (size_t)b * (FH * FW) * FC;

#pragma unroll
    for (int j = 0; j < 32; j += 8)
        tile[ty + j][tx] = inb[(size_t)(c0 + ty + j) * (FH * FW) + (p0 + tx)];
    __syncthreads();
#pragma unroll
    for (int j = 0; j < 32; j += 8)
        outb[(size_t)(p0 + ty + j) * FC + (c0 + tx)] = tile[tx][ty + j];
}

// ---------------------------------------------------------------------------
// Main kernel, NHWC path. grid (R, 4) x 64 threads.
// blockIdx.y = bin quarter (13,13,13,10 bins); thread t owns channels
// [4t, 4t+4) via float4 loads (1 KiB contiguous per wave per corner).
// ---------------------------------------------------------------------------
__global__ __launch_bounds__(64)
void roi_nhwc_kernel(const float* __restrict__ feat,
                     const float* __restrict__ rois,
                     float* __restrict__ out)
{
    int r    = blockIdx.x;
    int q    = blockIdx.y;
    int bin0 = q * 13;
    int nb   = (bin0 + 13 <= NBIN) ? 13 : (NBIN - bin0);
    int tid  = threadIdx.x;

    __shared__ float4 s_w[52];
    __shared__ int4   s_o[52];

    const float* roi = rois + r * 6;
    int ns = nb * 4;
    if (tid < ns) {
        float4 w; int4 o;
        compute_sample(roi, bin0 * 4 + tid, true, &w, &o);
        s_w[tid] = w;
        s_o[tid] = o;
    }
    __syncthreads();

    const float* fbase = feat + tid * 4;   // this thread's 4-channel group
    float* obase = out + (size_t)r * (FC * NBIN) + (size_t)(tid * 4) * NBIN + bin0;

    for (int lb = 0; lb < nb; ++lb) {
        float4 a = make_float4(0.0f, 0.0f, 0.0f, 0.0f);
#pragma unroll
        for (int k = 0; k < 4; ++k) {
            float4 w = s_w[lb * 4 + k];
            int4   o = s_o[lb * 4 + k];
            float4 f0 = *(const float4*)(fbase + o.x);
            float4 f1 = *(const float4*)(fbase + o.y);
            float4 f2 = *(const float4*)(fbase + o.z);
            float4 f3 = *(const float4*)(fbase + o.w);
            a.x += w.x * f0.x + w.y * f1.x + w.z * f2.x + w.w * f3.x;
            a.y += w.x * f0.y + w.y * f1.y + w.z * f2.y + w.w * f3.y;
            a.z += w.x * f0.z + w.y * f1.z + w.z * f2.z + w.w * f3.z;
            a.w += w.x * f0.w + w.y * f1.w + w.z * f2.w + w.w * f3.w;
        }
        obase[0 * NBIN + lb] = fixnum(a.x);
        obase[1 * NBIN + lb] = fixnum(a.y);
        obase[2 * NBIN + lb] = fixnum(a.z);
        obase[3 * NBIN + lb] = fixnum(a.w);
    }
}

// ---------------------------------------------------------------------------
// Fallback (ws too small for NHWC copy): direct NCHW, 256 threads = channels.
// Uncoalesced (stride H*W) but correct.
// ---------------------------------------------------------------------------
__global__ __launch_bounds__(256)
void roi_nchw_kernel(const float* __restrict__ feat,
                     const float* __restrict__ rois,
                     float* __restrict__ out)
{
    int r   = blockIdx.x;
    int tid = threadIdx.x;   // channel

    __shared__ float4 s_w[NSAMP];
    __shared__ int4   s_o[NSAMP];

    const float* roi = rois + r * 6;
    if (tid < NSAMP) {
        float4 w; int4 o;
        compute_sample(roi, tid, false, &w, &o);
        s_w[tid] = w;
        s_o[tid] = o;
    }
    __syncthreads();

    const float* fc = feat + (size_t)tid * (FH * FW);
    float* obase = out + (size_t)r * (FC * NBIN) + (size_t)tid * NBIN;

    for (int bin = 0; bin < NBIN; ++bin) {
        float a = 0.0f;
#pragma unroll
        for (int k = 0; k < 4; ++k) {
            float4 w = s_w[bin * 4 + k];
            int4   o = s_o[bin * 4 + k];
            a += w.x * fc[o.x] + w.y * fc[o.y] + w.z * fc[o.z] + w.w * fc[o.w];
        }
        obase[bin] = fixnum(a);
    }
}

extern "C" void kernel_launch(void* const* d_in, const int* in_sizes, int n_in,
                              void* d_out, int out_size, void* d_ws, size_t ws_size,
                              hipStream_t stream)
{
    const float* feat = (const float*)d_in[0];
    const float* rois = (const float*)d_in[1];
    float* out = (float*)d_out;

    int R = in_sizes[1] / 6;
    int N = in_sizes[0] / (FC * FH * FW);
    size_t need = (size_t)in_sizes[0] * sizeof(float);

    if (ws_size >= need) {
        float* featT = (float*)d_ws;
        dim3 tb(32, 8, 1);
        dim3 tg((FH * FW) / 32, FC / 32, N);
        transpose_kernel<<<tg, tb, 0, stream>>>(feat, featT);
        dim3 g(R, 4, 1);
        roi_nhwc_kernel<<<g, 64, 0, stream>>>(featT, rois, out);
    } else {
        roi_nchw_kernel<<<R, 256, 0, stream>>>(feat, rois, out);
    }
}

// Round 2
// 177.274 us; speedup vs baseline: 1.8400x; 1.8400x over previous
//
#include <hip/hip_runtime.h>
#include <hip/hip_fp16.h>

#define FH 200
#define FW 200
#define FC 256
#define NBIN 49      // 7*7 output bins
#define NSAMP 196    // NBIN * 4 subsamples
#define OUTS_STRIDE 260   // LDS out-staging channel stride (floats); 260*4 B, 16B-aligned, breaks bank pattern

// ---------------------------------------------------------------------------
// Per-sample geometry: weights (pre-multiplied by valid-mask and 0.25 mean
// factor) and 4 bilinear-corner offsets (in ELEMENTS of the chosen layout).
// Matches the JAX reference (aligned coords, clamp-at-edge, valid in [-1,H]).
// ---------------------------------------------------------------------------
__device__ __forceinline__ void compute_sample(const float* __restrict__ roi,
                                               int s, bool nhwc,
                                               float4* wout, int4* oout)
{
    int   b  = (int)roi[0];
    float cw = roi[1] * 0.25f - 0.5f;
    float ch = roi[2] * 0.25f - 0.5f;
    float rw = fmaxf(roi[3] * 0.25f, 1.0f);
    float rh = fmaxf(roi[4] * 0.25f, 1.0f);
    float th = roi[5] * 0.017453292519943295f;   // pi/180
    float ct = cosf(th);
    float st = sinf(th);
    float bin_h = rh / 7.0f;
    float bin_w = rw / 7.0f;

    int bin = s >> 2;
    int sub = s & 3;
    int iy  = sub >> 1;
    int ix  = sub & 1;
    int ph  = bin / 7;
    int pw  = bin - ph * 7;

    float fy = 0.25f + 0.5f * (float)iy;  // frac = {0.25, 0.75}
    float fx = 0.25f + 0.5f * (float)ix;
    float yy = -rh * 0.5f + ((float)ph + fy) * bin_h;
    float xx = -rw * 0.5f + ((float)pw + fx) * bin_w;
    float y  = yy * ct - xx * st + ch;
    float x  = yy * st + xx * ct + cw;

    bool valid = (y >= -1.0f) && (y <= (float)FH) && (x >= -1.0f) && (x <= (float)FW);
    y = fmaxf(y, 0.0f);
    x = fmaxf(x, 0.0f);
    int y0 = (int)floorf(y);
    int x0 = (int)floorf(x);
    bool cy = (y0 >= FH - 1);
    bool cx = (x0 >= FW - 1);
    int ylo = cy ? (FH - 1) : y0;
    int yhi = cy ? (FH - 1) : (y0 + 1);
    int xlo = cx ? (FW - 1) : x0;
    int xhi = cx ? (FW - 1) : (x0 + 1);
    float ly = cy ? 0.0f : (y - (float)y0);
    float lx = cx ? 0.0f : (x - (float)x0);
    float hy = 1.0f - ly;
    float hx = 1.0f - lx;
    float m  = valid ? 0.25f : 0.0f;   // fold valid-mask + mean(4 samples)

    *wout = make_float4(hy * hx * m, hy * lx * m, ly * hx * m, ly * lx * m);

    int bb = b * (FC * FH * FW);
    int p0 = ylo * FW + xlo;
    int p1 = ylo * FW + xhi;
    int p2 = yhi * FW + xlo;
    int p3 = yhi * FW + xhi;
    if (nhwc)
        *oout = make_int4(bb + p0 * FC, bb + p1 * FC, bb + p2 * FC, bb + p3 * FC);
    else
        *oout = make_int4(bb + p0, bb + p1, bb + p2, bb + p3);
}

__device__ __forceinline__ float fixnum(float v)
{
    return (v == v && v <= 3.402823466e38f && v >= -3.402823466e38f) ? v : 1e-8f;
}

// ---------------------------------------------------------------------------
// NCHW f32 -> NHWC fp16 transpose. Tile = 64 ch x 32 px. Block 256.
// grid ((H*W)/32, C/64, N).
// Phase 1: coalesced float4 reads (4 px of one ch), cvt, scatter b16 to LDS.
// Phase 2: one ds_read_b128 (8 contiguous ch halves) + one 16 B global store.
// ---------------------------------------------------------------------------
__global__ __launch_bounds__(256)
void transpose_f16_kernel(const float* __restrict__ in, __half* __restrict__ out)
{
    __shared__ __half tileT[32][72];   // [px][ch], stride 144 B (16B-aligned)
    int b   = blockIdx.z;
    int p0  = blockIdx.x * 32;
    int c0  = blockIdx.y * 64;
    int tid = threadIdx.x;

    const float* inb  = in  + (size_t)b * FC * (FH * FW);
    __half*      outb = out + (size_t)b * (FH * FW) * FC;

#pragma unroll
    for (int k = 0; k < 2; ++k) {
        int chl = k * 32 + (tid >> 3);       // 0..63 local channel
        int px4 = (tid & 7) * 4;             // 0,4,..,28 local pixel
        float4 v = *(const float4*)(inb + (size_t)(c0 + chl) * (FH * FW) + p0 + px4);
        tileT[px4 + 0][chl] = __float2half(v.x);
        tileT[px4 + 1][chl] = __float2half(v.y);
        tileT[px4 + 2][chl] = __float2half(v.z);
        tileT[px4 + 3][chl] = __float2half(v.w);
    }
    __syncthreads();

    int p  = tid >> 3;        // 0..31
    int h8 = (tid & 7) * 8;   // 0,8,..,56
    uint4 d = *(const uint4*)&tileT[p][h8];
    *(uint4*)(outb + (size_t)(p0 + p) * FC + c0 + h8) = d;
}

// ---------------------------------------------------------------------------
// Main kernel: one block (256 thr = 4 waves) per RoI.
// Half-wave (32 lanes) owns one bin at a time; lane owns 8 channels
// (one 16 B fp16 load per corner -> 512 B contiguous per half-wave).
// Output staged in LDS [bin][ch] then dumped with coalesced float4 stores
// (each RoI's 50176 B output region is exactly line-aligned -> no RMW).
// ---------------------------------------------------------------------------
__global__ __launch_bounds__(256)
void roi_nhwc_f16_kernel(const __half* __restrict__ feat,
                         const float* __restrict__ rois,
                         float* __restrict__ out)
{
    __shared__ float4 s_w[NSAMP];
    __shared__ int4   s_o[NSAMP];
    __shared__ float  out_s[NBIN * OUTS_STRIDE];

    int r   = blockIdx.x;
    int tid = threadIdx.x;

    const float* roi = rois + r * 6;
    if (tid < NSAMP) {
        float4 w; int4 o;
        compute_sample(roi, tid, true, &w, &o);
        s_w[tid] = w;
        s_o[tid] = o;
    }
    __syncthreads();

    int w    = tid >> 6;          // wave 0..3
    int lane = tid & 63;
    int s2   = lane >> 5;         // half-wave
    int ch8  = (lane & 31) * 8;   // this lane's 8 channels

    for (int p = w; p < 25; p += 4) {
        int bin = p * 2 + s2;
        if (bin < NBIN) {
            float acc[8];
#pragma unroll
            for (int i = 0; i < 8; ++i) acc[i] = 0.0f;

#pragma unroll
            for (int sub = 0; sub < 4; ++sub) {
                int s = bin * 4 + sub;
                float4 wt = s_w[s];
                int4   o  = s_o[s];
                uint4 u0 = *(const uint4*)(feat + o.x + ch8);
                uint4 u1 = *(const uint4*)(feat + o.y + ch8);
                uint4 u2 = *(const uint4*)(feat + o.z + ch8);
                uint4 u3 = *(const uint4*)(feat + o.w + ch8);
                const __half2* h0 = (const __half2*)&u0;
                const __half2* h1 = (const __half2*)&u1;
                const __half2* h2 = (const __half2*)&u2;
                const __half2* h3 = (const __half2*)&u3;
#pragma unroll
                for (int j = 0; j < 4; ++j) {
                    float2 f0 = __half22float2(h0[j]);
                    float2 f1 = __half22float2(h1[j]);
                    float2 f2 = __half22float2(h2[j]);
                    float2 f3 = __half22float2(h3[j]);
                    acc[2 * j + 0] += wt.x * f0.x + wt.y * f1.x + wt.z * f2.x + wt.w * f3.x;
                    acc[2 * j + 1] += wt.x * f0.y + wt.y * f1.y + wt.z * f2.y + wt.w * f3.y;
                }
            }
            float* dst = &out_s[bin * OUTS_STRIDE + ch8];
            *(float4*)(dst + 0) = make_float4(acc[0], acc[1], acc[2], acc[3]);
            *(float4*)(dst + 4) = make_float4(acc[4], acc[5], acc[6], acc[7]);
        }
    }
    __syncthreads();

    // Dump LDS [bin][ch] -> global [ch][bin], fully coalesced float4 stores.
    float* obase = out + (size_t)r * (FC * NBIN);
    for (int v4 = tid; v4 < (FC * NBIN) / 4; v4 += 256) {
        int f0 = v4 * 4;
        float vals[4];
#pragma unroll
        for (int i = 0; i < 4; ++i) {
            int f = f0 + i;
            int c = f / NBIN;
            int b = f - c * NBIN;
            vals[i] = fixnum(out_s[b * OUTS_STRIDE + c]);
        }
        *(float4*)(obase + f0) = make_float4(vals[0], vals[1], vals[2], vals[3]);
    }
}

// ---------------------------------------------------------------------------
// Fallback (ws too small): direct NCHW, correct but slow.
// ---------------------------------------------------------------------------
__global__ __launch_bounds__(256)
void roi_nchw_kernel(const float* __restrict__ feat,
                     const float* __restrict__ rois,
                     float* __restrict__ out)
{
    int r   = blockIdx.x;
    int tid = threadIdx.x;

    __shared__ float4 s_w[NSAMP];
    __shared__ int4   s_o[NSAMP];

    const float* roi = rois + r * 6;
    if (tid < NSAMP) {
        float4 w; int4 o;
        compute_sample(roi, tid, false, &w, &o);
        s_w[tid] = w;
        s_o[tid] = o;
    }
    __syncthreads();

    const float* fc = feat + (size_t)tid * (FH * FW);
    float* obase = out + (size_t)r * (FC * NBIN) + (size_t)tid * NBIN;

    for (int bin = 0; bin < NBIN; ++bin) {
        float a = 0.0f;
#pragma unroll
        for (int k = 0; k < 4; ++k) {
            float4 w = s_w[bin * 4 + k];
            int4   o = s_o[bin * 4 + k];
            a += w.x * fc[o.x] + w.y * fc[o.y] + w.z * fc[o.z] + w.w * fc[o.w];
        }
        obase[bin] = fixnum(a);
    }
}

extern "C" void kernel_launch(void* const* d_in, const int* in_sizes, int n_in,
                              void* d_out, int out_size, void* d_ws, size_t ws_size,
                              hipStream_t stream)
{
    const float* feat = (const float*)d_in[0];
    const float* rois = (const float*)d_in[1];
    float* out = (float*)d_out;

    int R = in_sizes[1] / 6;
    int N = in_sizes[0] / (FC * FH * FW);
    size_t need = (size_t)in_sizes[0] * sizeof(__half);

    if (ws_size >= need) {
        __half* featT = (__half*)d_ws;
        dim3 tb(256, 1, 1);
        dim3 tg((FH * FW) / 32, FC / 64, N);
        transpose_f16_kernel<<<tg, tb, 0, stream>>>(feat, featT);
        roi_nhwc_f16_kernel<<<R, 256, 0, stream>>>(featT, rois, out);
    } else {
        roi_nchw_kernel<<<R, 256, 0, stream>>>(feat, rois, out);
    }
}